// Round 1
// baseline (2452.035 us; speedup 1.0000x reference)
//
#include <hip/hip_runtime.h>
#include <math.h>

#define NN 50000
#define HH 128
#define KK 8

// workspace layout (float offsets)
#define WS_B    0         // 384x384 stacked B: rows 0:128=Wiou, 128:256=M0, 256:384=M1
#define WS_KV   147456    // 128x128 = Kf@vf
#define WS_T0   163840    // 128x128 = Kv@Wd
#define WS_T1   180224    // 128x128 = Kv@Wa
#define WS_kv   196608    // 128 = Kf@Vf
#define WS_qv   196736    // 128 = Qf@Vf
// total 196864 floats = 787456 bytes

__global__ void prep1(const float* __restrict__ Kf, const float* __restrict__ Qf,
                      const float* __restrict__ vf, const float* __restrict__ Vf,
                      const float* __restrict__ Wiou, float* __restrict__ ws) {
    int idx = blockIdx.x * 256 + threadIdx.x;
    if (idx < 16384) {
        int a = idx >> 7, c = idx & 127;
        float s = 0.f;
        for (int b = 0; b < 128; ++b) s += Kf[a * 128 + b] * vf[b * 128 + c];
        ws[WS_KV + idx] = s;
    } else if (idx < 16512) {
        int a = idx - 16384;
        float s = 0.f;
        for (int b = 0; b < 128; ++b) s += Kf[a * 128 + b] * Vf[b];
        ws[WS_kv + a] = s;
    } else if (idx < 16640) {
        int a = idx - 16512;
        float s = 0.f;
        for (int b = 0; b < 128; ++b) s += Qf[a * 128 + b] * Vf[b];
        ws[WS_qv + a] = s;
    } else if (idx < 16640 + 49152) {
        int i = idx - 16640;
        ws[WS_B + i] = Wiou[i];   // rows 0:128 of stacked B
    }
}

__global__ void prep2(const float* __restrict__ Wd, const float* __restrict__ Wa,
                      float* __restrict__ ws) {
    int idx = blockIdx.x * 256 + threadIdx.x;   // 32768 tasks
    int sel = idx >> 14;                         // 0 -> T0 (Wd), 1 -> T1 (Wa)
    int r = (idx >> 7) & 127, c = idx & 127;
    const float* W = sel ? Wa : Wd;
    const float* Kv = ws + WS_KV;
    float s = 0.f;
    for (int h = 0; h < 128; ++h) s += Kv[r * 128 + h] * W[h * 128 + c];
    ws[(sel ? WS_T1 : WS_T0) + r * 128 + c] = s;
}

__global__ void prep3(const float* __restrict__ Uiou, float* __restrict__ ws) {
    int idx = blockIdx.x * 256 + threadIdx.x;   // 98304 tasks
    int half = (idx >= 49152) ? 1 : 0;
    int i2 = idx - half * 49152;
    int r = i2 / 384, c = i2 % 384;
    const float* T = ws + (half ? WS_T1 : WS_T0);
    const float* U = Uiou + half * 128 * 384;
    float s = 0.f;
    for (int h = 0; h < 128; ++h) s += T[r * 128 + h] * U[h * 384 + c];
    ws[WS_B + (128 + half * 128 + r) * 384 + c] = s;
}

__device__ __forceinline__ float sigm(float v) { return 1.f / (1.f + expf(-v)); }

__global__ __launch_bounds__(256) void tree_main(
    const float* __restrict__ x, const float* __restrict__ h_mail,
    const float* __restrict__ c_mail, const float* __restrict__ biou,
    const float* __restrict__ Of, const float* __restrict__ Zf,
    const int* __restrict__ etype, const float* __restrict__ ws,
    float* __restrict__ out)
{
    __shared__ float G[16][388];   // [0:128)=x, [128:256)=sb*g0, [256:384)=sa*g1
    __shared__ float kvq[256];     // kv | qv

    const int t = threadIdx.x;
    const int n = t >> 4;          // node within tile (0..15)
    const int s = t & 15;          // lane-in-group
    const int node = blockIdx.x * 16 + n;
    const int rowbase = node * (KK * HH);

    // ---- phase 0: load x tile + kv/qv ----
    kvq[t] = ws[WS_kv + t];        // kv (0:128) and qv (128:256) are contiguous
    #pragma unroll
    for (int j = 0; j < 8; ++j) {
        int h = s + 16 * j;
        G[n][h] = x[node * HH + h];
    }
    __syncthreads();

    // ---- phase 1: w softmax coefficients, g0/g1 build ----
    int e[KK];
    #pragma unroll
    for (int k = 0; k < KK; ++k) e[k] = etype[node * KK + k];

    float xq = 0.f;
    #pragma unroll
    for (int j = 0; j < 8; ++j) {
        int h = s + 16 * j;
        xq += G[n][h] * kvq[128 + h];
    }
    float p[KK];
    #pragma unroll
    for (int k = 0; k < KK; ++k) {
        float acc = 0.f;
        #pragma unroll
        for (int j = 0; j < 8; ++j) {
            int h = s + 16 * j;
            acc += h_mail[rowbase + k * HH + h] * kvq[h];
        }
        p[k] = acc;
    }
    // butterfly reduce across the 16-thread group (all lanes end with the sum)
    #pragma unroll
    for (int m = 8; m >= 1; m >>= 1) {
        xq += __shfl_xor(xq, m, 16);
        #pragma unroll
        for (int k = 0; k < KK; ++k) p[k] += __shfl_xor(p[k], m, 16);
    }
    float esum = 0.f;
    #pragma unroll
    for (int k = 0; k < KK; ++k) esum += (float)e[k];
    const float mod = esum * 0.125f;
    const float sa = 1.f - mod, sb = mod;

    float tk[KK], mx = -1e30f;
    #pragma unroll
    for (int k = 0; k < KK; ++k) { tk[k] = tanhf(xq + p[k]); mx = fmaxf(mx, tk[k]); }
    float wsum = 0.f;
    #pragma unroll
    for (int k = 0; k < KK; ++k) { tk[k] = expf(tk[k] - mx); wsum += tk[k]; }
    const float inv = 1.f / wsum;
    float cf0[KK], cf1[KK];
    #pragma unroll
    for (int k = 0; k < KK; ++k) {
        float w = tk[k] * inv;
        cf0[k] = sb * w * (1.f - (float)e[k]);
        cf1[k] = sa * w * (float)e[k];
    }
    #pragma unroll
    for (int j = 0; j < 8; ++j) {
        int h = s + 16 * j;
        float a0 = 0.f, a1 = 0.f;
        #pragma unroll
        for (int k = 0; k < KK; ++k) {
            float v = h_mail[rowbase + k * HH + h];
            a0 += cf0[k] * v;
            a1 += cf1[k] * v;
        }
        G[n][128 + h] = a0;
        G[n][256 + h] = a1;
    }
    __syncthreads();

    // ---- phase 2: f = sigmoid(h_mail @ (e ? Of : Zf)), c_red = sum_k f*c_mail ----
    const int c0 = s * 8;
    float cred[8] = {0.f, 0.f, 0.f, 0.f, 0.f, 0.f, 0.f, 0.f};
    for (int k = 0; k < KK; ++k) {
        const float* W = e[k] ? Of : Zf;
        const float* hrow = h_mail + rowbase + k * HH;
        float F[8] = {0.f, 0.f, 0.f, 0.f, 0.f, 0.f, 0.f, 0.f};
        #pragma unroll 8
        for (int h4 = 0; h4 < 32; ++h4) {
            float4 av = ((const float4*)hrow)[h4];
            #pragma unroll
            for (int q = 0; q < 4; ++q) {
                int h = h4 * 4 + q;
                float a = (q == 0) ? av.x : (q == 1) ? av.y : (q == 2) ? av.z : av.w;
                float4 w0 = ((const float4*)(W + h * 128 + c0))[0];
                float4 w1 = ((const float4*)(W + h * 128 + c0))[1];
                F[0] += a * w0.x; F[1] += a * w0.y; F[2] += a * w0.z; F[3] += a * w0.w;
                F[4] += a * w1.x; F[5] += a * w1.y; F[6] += a * w1.z; F[7] += a * w1.w;
            }
        }
        const float* crow = c_mail + rowbase + k * HH + c0;
        float4 cm0 = ((const float4*)crow)[0];
        float4 cm1 = ((const float4*)crow)[1];
        cred[0] += sigm(F[0]) * cm0.x; cred[1] += sigm(F[1]) * cm0.y;
        cred[2] += sigm(F[2]) * cm0.z; cred[3] += sigm(F[3]) * cm0.w;
        cred[4] += sigm(F[4]) * cm1.x; cred[5] += sigm(F[5]) * cm1.y;
        cred[6] += sigm(F[6]) * cm1.z; cred[7] += sigm(F[7]) * cm1.w;
    }

    // ---- phase 3: iou = G @ Bws + biou, then epilogue ----
    float bi[8], bo[8], bu[8];
    #pragma unroll
    for (int j = 0; j < 8; ++j) {
        bi[j] = biou[c0 + j];
        bo[j] = biou[128 + c0 + j];
        bu[j] = biou[256 + c0 + j];
    }
    const float* Bws = ws + WS_B;
    #pragma unroll 4
    for (int jj = 0; jj < 384; ++jj) {
        float g = G[n][jj];
        const float* brow = Bws + jj * 384;
        float4 q0 = ((const float4*)(brow + c0))[0];
        float4 q1 = ((const float4*)(brow + c0))[1];
        float4 r0 = ((const float4*)(brow + 128 + c0))[0];
        float4 r1 = ((const float4*)(brow + 128 + c0))[1];
        float4 u0 = ((const float4*)(brow + 256 + c0))[0];
        float4 u1 = ((const float4*)(brow + 256 + c0))[1];
        bi[0] += g * q0.x; bi[1] += g * q0.y; bi[2] += g * q0.z; bi[3] += g * q0.w;
        bi[4] += g * q1.x; bi[5] += g * q1.y; bi[6] += g * q1.z; bi[7] += g * q1.w;
        bo[0] += g * r0.x; bo[1] += g * r0.y; bo[2] += g * r0.z; bo[3] += g * r0.w;
        bo[4] += g * r1.x; bo[5] += g * r1.y; bo[6] += g * r1.z; bo[7] += g * r1.w;
        bu[0] += g * u0.x; bu[1] += g * u0.y; bu[2] += g * u0.z; bu[3] += g * u0.w;
        bu[4] += g * u1.x; bu[5] += g * u1.y; bu[6] += g * u1.z; bu[7] += g * u1.w;
    }
    #pragma unroll
    for (int j = 0; j < 8; ++j) {
        float ii = sigm(bi[j]);
        float oo = sigm(bo[j]);
        float uu = tanhf(bu[j]);
        float c = ii * uu + cred[j];
        float h = oo * tanhf(c);
        out[node * HH + c0 + j] = h;
        out[NN * HH + node * HH + c0 + j] = c;
    }
}

extern "C" void kernel_launch(void* const* d_in, const int* in_sizes, int n_in,
                              void* d_out, int out_size, void* d_ws, size_t ws_size,
                              hipStream_t stream) {
    const float* x      = (const float*)d_in[0];
    const float* h_mail = (const float*)d_in[1];
    const float* c_mail = (const float*)d_in[2];
    const float* Wiou   = (const float*)d_in[3];
    const float* Uiou   = (const float*)d_in[4];
    const float* biou   = (const float*)d_in[5];
    const float* Of     = (const float*)d_in[6];
    const float* Zf     = (const float*)d_in[7];
    const float* Qf     = (const float*)d_in[8];
    const float* Kf     = (const float*)d_in[9];
    const float* vf     = (const float*)d_in[10];
    const float* Wa     = (const float*)d_in[11];
    const float* Wd     = (const float*)d_in[12];
    const float* Vf     = (const float*)d_in[13];
    const int*   etype  = (const int*)d_in[14];
    float* ws  = (float*)d_ws;
    float* out = (float*)d_out;

    hipLaunchKernelGGL(prep1, dim3(257), dim3(256), 0, stream, Kf, Qf, vf, Vf, Wiou, ws);
    hipLaunchKernelGGL(prep2, dim3(128), dim3(256), 0, stream, Wd, Wa, ws);
    hipLaunchKernelGGL(prep3, dim3(384), dim3(256), 0, stream, Uiou, ws);
    hipLaunchKernelGGL(tree_main, dim3(3125), dim3(256), 0, stream,
                       x, h_mail, c_mail, biou, Of, Zf, etype, ws, out);
}

// Round 2
// 747.686 us; speedup vs baseline: 3.2795x; 3.2795x over previous
//
#include <hip/hip_runtime.h>
#include <math.h>

#define NN 50000
#define HH 128
#define KK 8

// ws float offsets
#define WS_WTF  0         // [Of;Zf] transposed bf16: wtf[c*256+k], 32768 shorts = 16384 fslots
#define WS_BT   16384     // stacked B transposed bf16: bt[c*384+k], 147456 shorts = 73728 fslots
#define WS_KV   90112     // 128x128 f32 Kf@vf
#define WS_T0   106496    // 128x128 f32 KV@Wd
#define WS_T1   122880    // 128x128 f32 KV@Wa
#define WS_kv   139264    // 128 f32 Kf@Vf
#define WS_qv   139392    // 128 f32 Qf@Vf
// end 139520 floats = 558 KB

typedef __attribute__((ext_vector_type(8))) unsigned short u16x8;
typedef __attribute__((ext_vector_type(8))) __bf16 bf16x8;
typedef __attribute__((ext_vector_type(4))) float f32x4;
union Frag { u16x8 u; bf16x8 b; };

__device__ __forceinline__ unsigned short f2bf(float f) {
    unsigned u = __builtin_bit_cast(unsigned, f);
    u += 0x7fffu + ((u >> 16) & 1u);
    return (unsigned short)(u >> 16);
}
__device__ __forceinline__ float sigm(float v) { return 1.f / (1.f + expf(-v)); }

// ---- prep kernels ----
__global__ void prep1(const float* __restrict__ Kf, const float* __restrict__ Qf,
                      const float* __restrict__ vf, const float* __restrict__ Vf,
                      const float* __restrict__ Wiou, float* __restrict__ ws) {
    int idx = blockIdx.x * 256 + threadIdx.x;   // 65792 tasks
    unsigned short* bt = (unsigned short*)(ws + WS_BT);
    if (idx < 16384) {
        int a = idx >> 7, c = idx & 127;
        float s = 0.f;
        for (int b = 0; b < 128; ++b) s += Kf[a * 128 + b] * vf[b * 128 + c];
        ws[WS_KV + idx] = s;
    } else if (idx < 16512) {
        int a = idx - 16384;
        float s = 0.f;
        for (int b = 0; b < 128; ++b) s += Kf[a * 128 + b] * Vf[b];
        ws[WS_kv + a] = s;
    } else if (idx < 16640) {
        int a = idx - 16512;
        float s = 0.f;
        for (int b = 0; b < 128; ++b) s += Qf[a * 128 + b] * Vf[b];
        ws[WS_qv + a] = s;
    } else {
        int i = idx - 16640;                     // < 49152; Wiou rows 0..127 of B
        int r = i / 384, c = i % 384;
        bt[c * 384 + r] = f2bf(Wiou[i]);
    }
}

__global__ void prep2(const float* __restrict__ Wd, const float* __restrict__ Wa,
                      float* __restrict__ ws) {
    int idx = blockIdx.x * 256 + threadIdx.x;   // 32768 tasks
    int sel = idx >> 14;
    int r = (idx >> 7) & 127, c = idx & 127;
    const float* W = sel ? Wa : Wd;
    const float* Kv = ws + WS_KV;
    float s = 0.f;
    for (int h = 0; h < 128; ++h) s += Kv[r * 128 + h] * W[h * 128 + c];
    ws[(sel ? WS_T1 : WS_T0) + r * 128 + c] = s;
}

__global__ void prep3(const float* __restrict__ Uiou, float* __restrict__ ws) {
    int idx = blockIdx.x * 256 + threadIdx.x;   // 98304 tasks
    int half = (idx >= 49152) ? 1 : 0;
    int i2 = idx - half * 49152;
    int r = i2 / 384, c = i2 % 384;
    const float* T = ws + (half ? WS_T1 : WS_T0);
    const float* U = Uiou + half * 128 * 384;
    float s = 0.f;
    for (int h = 0; h < 128; ++h) s += T[r * 128 + h] * U[h * 384 + c];
    unsigned short* bt = (unsigned short*)(ws + WS_BT);
    bt[c * 384 + (128 + half * 128 + r)] = f2bf(s);   // B row = 128+half*128+r, transposed store
}

__global__ void prep4(const float* __restrict__ Of, const float* __restrict__ Zf,
                      float* __restrict__ ws) {
    int idx = blockIdx.x * 256 + threadIdx.x;   // 32768 tasks: wtf[c*256+k]
    int c = idx >> 8, k = idx & 255;
    float v = (k < 128) ? Of[k * 128 + c] : Zf[(k - 128) * 128 + c];
    unsigned short* wtf = (unsigned short*)(ws + WS_WTF);
    wtf[idx] = f2bf(v);
}

// ---- main fused kernel: 16 nodes / block, 256 threads ----
__global__ __launch_bounds__(256) void tree_main(
    const float* __restrict__ x, const float* __restrict__ h_mail,
    const float* __restrict__ c_mail, const float* __restrict__ biou,
    const int* __restrict__ etype, const float* __restrict__ ws,
    float* __restrict__ out)
{
    // G in MFMA-fragment order: GfS[(col>>3)*128 + node*8 + (col&7)], bf16
    __shared__ unsigned short GfS[48 * 128];     // 12288 B
    __shared__ float credS[16 * 128];            // 8192 B
    __shared__ float iouS[16 * 388];             // 24832 B
    __shared__ float efS[128];
    __shared__ float kvqS[256];

    const int t = threadIdx.x;
    const int node0 = blockIdx.x * 16;

    // ---------- phase A: attention coefficients + G build ----------
    {
        const int n = t >> 4, s = t & 15, c0 = s * 8;
        const int node = node0 + n;
        kvqS[t] = ws[WS_kv + t];                 // kv | qv contiguous
        if (t < 128) efS[t] = (float)etype[node0 * KK + t];

        float xv[8];
        const float4* xp = (const float4*)(x + node * HH + c0);
        float4 x0 = xp[0], x1 = xp[1];
        xv[0]=x0.x; xv[1]=x0.y; xv[2]=x0.z; xv[3]=x0.w;
        xv[4]=x1.x; xv[5]=x1.y; xv[6]=x1.z; xv[7]=x1.w;
        u16x8 xg;
        #pragma unroll
        for (int j = 0; j < 8; ++j) xg[j] = f2bf(xv[j]);
        *(u16x8*)(&GfS[s * 128 + n * 8]) = xg;   // cols 0..127 (col>>3 == s)
        __syncthreads();

        float xq = 0.f;
        #pragma unroll
        for (int j = 0; j < 8; ++j) xq += xv[j] * kvqS[128 + c0 + j];

        float p[KK];
        #pragma unroll
        for (int k = 0; k < KK; ++k) {
            const float4* hp = (const float4*)(h_mail + (node * KK + k) * HH + c0);
            float4 h0 = hp[0], h1 = hp[1];
            p[k] = h0.x*kvqS[c0]   + h0.y*kvqS[c0+1] + h0.z*kvqS[c0+2] + h0.w*kvqS[c0+3]
                 + h1.x*kvqS[c0+4] + h1.y*kvqS[c0+5] + h1.z*kvqS[c0+6] + h1.w*kvqS[c0+7];
        }
        #pragma unroll
        for (int msk = 8; msk >= 1; msk >>= 1) {
            xq += __shfl_xor(xq, msk, 16);
            #pragma unroll
            for (int k = 0; k < KK; ++k) p[k] += __shfl_xor(p[k], msk, 16);
        }
        float ef[KK], esum = 0.f;
        #pragma unroll
        for (int k = 0; k < KK; ++k) { ef[k] = efS[n * KK + k]; esum += ef[k]; }
        const float mod = esum * 0.125f;
        const float sa = 1.f - mod, sb = mod;

        float tk[KK], mx = -1e30f;
        #pragma unroll
        for (int k = 0; k < KK; ++k) { tk[k] = tanhf(xq + p[k]); mx = fmaxf(mx, tk[k]); }
        float wsum = 0.f;
        #pragma unroll
        for (int k = 0; k < KK; ++k) { tk[k] = expf(tk[k] - mx); wsum += tk[k]; }
        const float inv = 1.f / wsum;
        float cf0[KK], cf1[KK];
        #pragma unroll
        for (int k = 0; k < KK; ++k) {
            float w = tk[k] * inv;
            cf0[k] = sb * w * (1.f - ef[k]);
            cf1[k] = sa * w * ef[k];
        }
        float a0[8] = {0,0,0,0,0,0,0,0}, a1[8] = {0,0,0,0,0,0,0,0};
        #pragma unroll
        for (int k = 0; k < KK; ++k) {
            const float4* hp = (const float4*)(h_mail + (node * KK + k) * HH + c0);
            float4 h0 = hp[0], h1 = hp[1];
            float hv[8];
            hv[0]=h0.x; hv[1]=h0.y; hv[2]=h0.z; hv[3]=h0.w;
            hv[4]=h1.x; hv[5]=h1.y; hv[6]=h1.z; hv[7]=h1.w;
            #pragma unroll
            for (int j = 0; j < 8; ++j) { a0[j] += cf0[k]*hv[j]; a1[j] += cf1[k]*hv[j]; }
        }
        u16x8 g0, g1;
        #pragma unroll
        for (int j = 0; j < 8; ++j) { g0[j] = f2bf(a0[j]); g1[j] = f2bf(a1[j]); }
        *(u16x8*)(&GfS[(16 + s) * 128 + n * 8]) = g0;   // cols 128..255
        *(u16x8*)(&GfS[(32 + s) * 128 + n * 8]) = g1;   // cols 256..383
    }
    __syncthreads();

    // ---------- phase B: F-GEMM (K-doubled) + cred ----------
    const int wave = t >> 6, lane = t & 63, m = lane & 15, q = lane >> 4;
    {
        const unsigned short* WtF = (const unsigned short*)(ws + WS_WTF);
        f32x4 acc[2][8];
        #pragma unroll
        for (int rt = 0; rt < 2; ++rt)
            #pragma unroll
            for (int tc = 0; tc < 8; ++tc) acc[rt][tc] = (f32x4){0.f,0.f,0.f,0.f};

        #pragma unroll
        for (int ks = 0; ks < 8; ++ks) {
            const int kg = ks * 32 + q * 8;          // 0..255
            Frag bf[8], af[2];
            #pragma unroll
            for (int tc = 0; tc < 8; ++tc)
                bf[tc].u = *(const u16x8*)(WtF + (tc * 16 + m) * 256 + kg);
            #pragma unroll
            for (int rt = 0; rt < 2; ++rt) {
                const int r = wave * 32 + rt * 16 + m;
                const float msk = (ks < 4) ? efS[r] : (1.f - efS[r]);
                const float4* hp = (const float4*)(h_mail + (node0 * KK + r) * HH + (kg & 127));
                float4 h0 = hp[0], h1 = hp[1];
                float tv[8];
                tv[0]=h0.x*msk; tv[1]=h0.y*msk; tv[2]=h0.z*msk; tv[3]=h0.w*msk;
                tv[4]=h1.x*msk; tv[5]=h1.y*msk; tv[6]=h1.z*msk; tv[7]=h1.w*msk;
                #pragma unroll
                for (int j = 0; j < 8; ++j) af[rt].u[j] = f2bf(tv[j]);
            }
            #pragma unroll
            for (int rt = 0; rt < 2; ++rt)
                #pragma unroll
                for (int tc = 0; tc < 8; ++tc)
                    acc[rt][tc] = __builtin_amdgcn_mfma_f32_16x16x32_bf16(
                        af[rt].b, bf[tc].b, acc[rt][tc], 0, 0, 0);
        }
        // cred: sigmoid(F) * c_mail, summed over k (8 rows per node)
        #pragma unroll
        for (int rt = 0; rt < 2; ++rt) {
            const int rbase = wave * 32 + rt * 16;
            #pragma unroll
            for (int tc = 0; tc < 8; ++tc) {
                float sacc = 0.f;
                #pragma unroll
                for (int reg = 0; reg < 4; ++reg) {
                    const int r = rbase + q * 4 + reg;
                    const float f = sigm(acc[rt][tc][reg]);
                    sacc += f * c_mail[(node0 * KK + r) * HH + tc * 16 + m];
                }
                sacc += __shfl_xor(sacc, 16);
                if ((q & 1) == 0) {
                    const int nl = (rbase >> 3) + (q >> 1);
                    credS[nl * 128 + tc * 16 + m] = sacc;
                }
            }
        }
    }

    // ---------- phase C: iou = G @ B (K=384) ----------
    {
        const unsigned short* Bt = (const unsigned short*)(ws + WS_BT);
        f32x4 acc2[6];
        #pragma unroll
        for (int j = 0; j < 6; ++j) acc2[j] = (f32x4){0.f,0.f,0.f,0.f};
        #pragma unroll
        for (int ks = 0; ks < 12; ++ks) {
            const int kg = ks * 32 + q * 8;          // 0..383
            Frag ag;
            ag.u = *(const u16x8*)(&GfS[(kg >> 3) * 128 + m * 8]);
            #pragma unroll
            for (int j = 0; j < 6; ++j) {
                const int tc = wave * 6 + j;
                Frag bg;
                bg.u = *(const u16x8*)(Bt + (tc * 16 + m) * 384 + kg);
                acc2[j] = __builtin_amdgcn_mfma_f32_16x16x32_bf16(
                    ag.b, bg.b, acc2[j], 0, 0, 0);
            }
        }
        #pragma unroll
        for (int j = 0; j < 6; ++j) {
            const int tc = wave * 6 + j;
            #pragma unroll
            for (int reg = 0; reg < 4; ++reg)
                iouS[(q * 4 + reg) * 388 + tc * 16 + m] = acc2[j][reg];
        }
    }
    __syncthreads();

    // ---------- epilogue ----------
    {
        const int n = t >> 4, s = t & 15, c0 = s * 8;
        const int node = node0 + n;
        float hb[8], cb[8];
        #pragma unroll
        for (int j = 0; j < 8; ++j) {
            const int c = c0 + j;
            const float ii = sigm(iouS[n * 388 + c] + biou[c]);
            const float oo = sigm(iouS[n * 388 + 128 + c] + biou[128 + c]);
            const float uu = tanhf(iouS[n * 388 + 256 + c] + biou[256 + c]);
            const float cc = ii * uu + credS[n * 128 + c];
            cb[j] = cc;
            hb[j] = oo * tanhf(cc);
        }
        float4* oh = (float4*)(out + node * HH + c0);
        oh[0] = make_float4(hb[0], hb[1], hb[2], hb[3]);
        oh[1] = make_float4(hb[4], hb[5], hb[6], hb[7]);
        float4* oc = (float4*)(out + NN * HH + node * HH + c0);
        oc[0] = make_float4(cb[0], cb[1], cb[2], cb[3]);
        oc[1] = make_float4(cb[4], cb[5], cb[6], cb[7]);
    }
}

extern "C" void kernel_launch(void* const* d_in, const int* in_sizes, int n_in,
                              void* d_out, int out_size, void* d_ws, size_t ws_size,
                              hipStream_t stream) {
    const float* x      = (const float*)d_in[0];
    const float* h_mail = (const float*)d_in[1];
    const float* c_mail = (const float*)d_in[2];
    const float* Uiou   = (const float*)d_in[4];
    const float* biou   = (const float*)d_in[5];
    const float* Of     = (const float*)d_in[6];
    const float* Zf     = (const float*)d_in[7];
    const float* Qf     = (const float*)d_in[8];
    const float* Kf     = (const float*)d_in[9];
    const float* vf     = (const float*)d_in[10];
    const float* Wa     = (const float*)d_in[11];
    const float* Wd     = (const float*)d_in[12];
    const float* Vf     = (const float*)d_in[13];
    const int*   etype  = (const int*)d_in[14];
    const float* Wiou   = (const float*)d_in[3];
    float* ws  = (float*)d_ws;
    float* out = (float*)d_out;

    hipLaunchKernelGGL(prep1, dim3(257), dim3(256), 0, stream, Kf, Qf, vf, Vf, Wiou, ws);
    hipLaunchKernelGGL(prep2, dim3(128), dim3(256), 0, stream, Wd, Wa, ws);
    hipLaunchKernelGGL(prep3, dim3(384), dim3(256), 0, stream, Uiou, ws);
    hipLaunchKernelGGL(prep4, dim3(128), dim3(256), 0, stream, Of, Zf, ws);
    hipLaunchKernelGGL(tree_main, dim3(3125), dim3(256), 0, stream,
                       x, h_mail, c_mail, biou, etype, ws, out);
}